// Round 1
// 374.004 us; speedup vs baseline: 1.0176x; 1.0176x over previous
//
#include <hip/hip_runtime.h>

typedef unsigned short ushort_t;
typedef __attribute__((ext_vector_type(8))) short short8;
typedef __attribute__((ext_vector_type(4))) float float4v;
typedef __attribute__((ext_vector_type(4))) ushort_t ushort4v;

#define B_ROWS 8192
#define HDIM   1024
#define GLD    5120   // G cols: [hat(c) | hat_raw | r | z | xh]

__device__ __forceinline__ float bf2f(ushort_t u) {
    return __uint_as_float(((unsigned)u) << 16);
}
__device__ __forceinline__ ushort_t f2bf(float f) {
    unsigned u = __float_as_uint(f);
    u += 0x7FFFu + ((u >> 16) & 1u);   // round-to-nearest-even
    return (ushort_t)(u >> 16);
}

// ---- one pack kernel for A, W, Whh ----------------------------------------
__global__ __launch_bounds__(256) void pack_all(
    const float* __restrict__ x, const float* __restrict__ h,
    const float* __restrict__ wc, const float* __restrict__ what,
    const float* __restrict__ wxr, const float* __restrict__ whr,
    const float* __restrict__ wxz, const float* __restrict__ whz,
    const float* __restrict__ wxh, const float* __restrict__ whh,
    ushort_t* __restrict__ A, ushort_t* __restrict__ W,
    ushort_t* __restrict__ Whh)
{
    const int bid = blockIdx.x;
    float4v v;
    ushort_t* dst;
    size_t i4;
    if (bid < 16384) {                       // ---- A = [x | hidden]
        i4 = ((size_t)bid * 256 + threadIdx.x) * 4;
        int c = (int)(i4 & 2047);
        size_t b = i4 >> 11;
        const float* src = (c < 1024) ? (x + b * 1024 + c)
                                      : (h + b * 1024 + (c - 1024));
        v = *(const float4v*)src;
        dst = A + i4;
    } else if (bid < 26624) {                // ---- W rows: wc|what|[xr|hr]|[xz|hz]|[xh|junk]
        i4 = ((size_t)(bid - 16384) * 256 + threadIdx.x) * 4;
        int j = (int)(i4 >> 11);
        int k = (int)(i4 & 2047);
        int r = j >> 10, jr = j & 1023;
        if (r == 0) {
            v = *(const float4v*)(wc + (size_t)j * 2048 + k);
        } else if (r == 1) {
            v = *(const float4v*)(what + (size_t)jr * 2048 + k);
        } else if (r == 4) {
            v = (k < 1024) ? *(const float4v*)(wxh + (size_t)jr * 1024 + k)
                           : (float4v){0.f, 0.f, 0.f, 0.f};
        } else {
            const float* p0 = (r == 2) ? wxr : wxz;
            const float* p1 = (r == 2) ? whr : whz;
            const float* p = (k < 1024) ? (p0 + (size_t)jr * 1024 + k)
                                        : (p1 + (size_t)jr * 1024 + (k - 1024));
            v = *(const float4v*)p;
        }
        dst = W + i4;
    } else {                                 // ---- Whh
        i4 = ((size_t)(bid - 26624) * 256 + threadIdx.x) * 4;
        v = *(const float4v*)(whh + i4);
        dst = Whh + i4;
    }
    ushort4v o;
#pragma unroll
    for (int t = 0; t < 4; ++t) o[t] = f2bf(v[t]);
    *(ushort4v*)dst = o;
}

// ---- GEMM1: G = A @ W^T -----------------------------------------------------
// 256x256 tile, BK=64, 8 waves, 8-phase schedule with counted vmcnt (T2+T3+T4+T5).
// LDS = 128 KiB: per operand 2 slots (K-tile parity) x 2 k-halves (32-k each) of
// 256x32 bf16 (16 KiB). Staging ring: each phase overwrites the k-half last read
// one phase earlier; vmcnt(6) at phases 4/8 keeps 3 half-tiles in flight across
// barriers (never a full drain in the main loop).
// Read swizzle on 16B chunks: chunk' = kc ^ (row&3) ^ ((row>>2)&1) -> each
// 16-lane ds_read_b128 group covers all 8 bank-groups exactly twice (free).
// Global source is pre-swizzled; LDS dest stays linear (global_load_lds rule).

#define GLOAD(gp, lp) __builtin_amdgcn_global_load_lds( \
    (const __attribute__((address_space(1))) void*)(gp), \
    (__attribute__((address_space(3))) void*)(lp), 16, 0, 0)

#define BARRIER __builtin_amdgcn_s_barrier()
#define WAITLGKM do { \
    asm volatile("s_waitcnt lgkmcnt(0)" ::: "memory"); \
    __builtin_amdgcn_sched_barrier(0); } while (0)
#define WAITVM6 do { \
    asm volatile("s_waitcnt vmcnt(6)" ::: "memory"); \
    __builtin_amdgcn_sched_barrier(0); } while (0)
#define WAITVM0 do { \
    asm volatile("s_waitcnt vmcnt(0)" ::: "memory"); \
    __builtin_amdgcn_sched_barrier(0); } while (0)

#define LOAD_A4(OFF, MI0) \
    _Pragma("unroll") \
    for (int mi = 0; mi < 4; ++mi) \
        af[mi] = *(const short8*)(Ard + (OFF) + ((MI0) + mi) * 512);

#define LOAD_B4(OFF) \
    _Pragma("unroll") \
    for (int ni = 0; ni < 4; ++ni) \
        bf[ni] = *(const short8*)(Brd + (OFF) + ni * 512);

#define STAGE_A(KH, OFF) do { \
    GLOAD(a_src0 + (KH) * 32, a_dst + (OFF)); \
    GLOAD(a_src1 + (KH) * 32, a_dst + (OFF) + 4096); } while (0)

#define STAGE_B(KH, OFF) do { \
    GLOAD(b_src0 + (KH) * 32, b_dst + (OFF)); \
    GLOAD(b_src1 + (KH) * 32, b_dst + (OFF) + 4096); } while (0)

#define MFMA_BLK(R) do { \
    __builtin_amdgcn_s_setprio(1); \
    _Pragma("unroll") \
    for (int mi = 0; mi < 4; ++mi) { \
        _Pragma("unroll") \
        for (int ni = 0; ni < 4; ++ni) \
            acc[(R) + mi][ni] = __builtin_amdgcn_mfma_f32_16x16x32_bf16( \
                af[mi], bf[ni], acc[(R) + mi][ni], 0, 0, 0); \
    } \
    __builtin_amdgcn_s_setprio(0); } while (0)

__global__ __launch_bounds__(512, 2) void gemm1(
    const ushort_t* __restrict__ A, const ushort_t* __restrict__ B,
    ushort_t* __restrict__ C)
{
    // XCD-bijective swizzle: 640 blocks = 8 * 80
    const int bid = blockIdx.x;
    const int swz = (bid & 7) * 80 + (bid >> 3);
    const int bx = swz % 20;
    const int by = swz / 20;
    const int bn0 = bx * 256;
    const int bm0 = by * 256;
    const int K = (bn0 >= 4096) ? 1024 : 2048;   // xh region has K=1024
    const int NIT = K >> 7;                      // 2 K-tiles (128 k) per iter

    __shared__ ushort_t lds[65536];              // 128 KiB
    // element offsets: A(slot,ks) = slot*16384 + ks*8192
    //                  B(slot,ks) = 32768 + slot*16384 + ks*8192

    const int t = threadIdx.x;
    const int wave = t >> 6, lane = t & 63;
    const int wm = wave >> 2, wn = wave & 3;     // 2M x 4N wave grid
    const int q = lane >> 4, r16 = lane & 15;

    // ---- ds_read addressing (per-lane, swizzled) ----
    const int s_l = (r16 & 3) ^ ((r16 >> 2) & 1);
    const int lane_rd = r16 * 32 + ((q ^ s_l) << 3);
    const ushort_t* Ard = lds + wm * 4096 + lane_rd;
    const ushort_t* Brd = lds + 32768 + wn * 2048 + lane_rd;

    // ---- staging addressing: chunk c = j*512 + t; row = c>>2, kc pre-swizzled
    const int srow = t >> 2;                                   // 0..127
    const int kc = (t & 3) ^ ((t >> 2) & 3) ^ ((t >> 4) & 1);
    const int kcOff = kc << 3;
    const ushort_t* a_src0 = A + (size_t)(bm0 + srow) * 2048 + kcOff;
    const ushort_t* a_src1 = a_src0 + (size_t)128 * 2048;
    const ushort_t* b_src0 = B + (size_t)(bn0 + srow) * 2048 + kcOff;
    const ushort_t* b_src1 = b_src0 + (size_t)128 * 2048;
    ushort_t* a_dst = lds + wave * 512;          // + slot*16384 + ks*8192 + j*4096
    ushort_t* b_dst = lds + 32768 + wave * 512;

    float4v acc[8][4];
#pragma unroll
    for (int i = 0; i < 8; ++i)
#pragma unroll
        for (int j = 0; j < 4; ++j)
            acc[i][j] = {0.f, 0.f, 0.f, 0.f};

    short8 af[4], bf[4];

    // ---- prologue: stage K-tile0 (4 halves) + A(1,0), B(1,0), B(1,1) ----
    STAGE_A(0, 0);      STAGE_B(0, 0);       // kh0: slot0 ks0
    STAGE_A(1, 8192);   STAGE_B(1, 8192);    // kh1: slot0 ks1
    STAGE_A(2, 16384);  STAGE_B(2, 16384);   // kh2: slot1 ks0
    STAGE_B(3, 24576);                       // kh3: slot1 ks1 (B only; A at P1)
    WAITVM6;                                 // oldest 4 halves (K-tile 0) done
    BARRIER;

    // ---- main loop: iterations 0..NIT-2 (steady), last peeled ----
#pragma unroll 1
    for (int it = 0; it < NIT - 1; ++it) {
        const int kh0 = it << 2;
        // P1: K-tile even, ks0, mi 0-3  | stage A(odd,1)
        LOAD_A4(0, 0); LOAD_B4(0);
        STAGE_A(kh0 + 3, 24576);
        BARRIER; WAITLGKM; MFMA_BLK(0); BARRIER;
        // P2: ks0, mi 4-7               | stage B(+2,0)
        LOAD_A4(0, 4);
        STAGE_B(kh0 + 4, 0);
        BARRIER; WAITLGKM; MFMA_BLK(4); BARRIER;
        // P3: ks1, mi 0-3               | stage A(+2,0)
        LOAD_A4(8192, 0); LOAD_B4(8192);
        STAGE_A(kh0 + 4, 0);
        BARRIER; WAITLGKM; MFMA_BLK(0); BARRIER;
        // P4: ks1, mi 4-7               | stage B(+2,1) ; vmcnt(6)
        LOAD_A4(8192, 4);
        STAGE_B(kh0 + 5, 8192);
        BARRIER; WAITLGKM; MFMA_BLK(4);
        WAITVM6;
        BARRIER;
        // P5: K-tile odd, ks0, mi 0-3   | stage A(+2,1)
        LOAD_A4(16384, 0); LOAD_B4(16384);
        STAGE_A(kh0 + 5, 8192);
        BARRIER; WAITLGKM; MFMA_BLK(0); BARRIER;
        // P6: ks0, mi 4-7               | stage B(+3,0)
        LOAD_A4(16384, 4);
        STAGE_B(kh0 + 6, 16384);
        BARRIER; WAITLGKM; MFMA_BLK(4); BARRIER;
        // P7: ks1, mi 0-3               | stage A(+3,0)
        LOAD_A4(24576, 0); LOAD_B4(24576);
        STAGE_A(kh0 + 6, 16384);
        BARRIER; WAITLGKM; MFMA_BLK(0); BARRIER;
        // P8: ks1, mi 4-7               | stage B(+3,1) ; vmcnt(6)
        LOAD_A4(24576, 4);
        STAGE_B(kh0 + 7, 24576);
        BARRIER; WAITLGKM; MFMA_BLK(4);
        WAITVM6;
        BARRIER;
    }

    // ---- peeled last iteration (no fresh stages beyond A(last,1)) ----
    {
        const int kh0 = (NIT - 1) << 2;
        LOAD_A4(0, 0); LOAD_B4(0);
        STAGE_A(kh0 + 3, 24576);
        BARRIER; WAITLGKM; MFMA_BLK(0); BARRIER;
        LOAD_A4(0, 4);
        BARRIER; WAITLGKM; MFMA_BLK(4); BARRIER;
        LOAD_A4(8192, 0); LOAD_B4(8192);
        BARRIER; WAITLGKM; MFMA_BLK(0); BARRIER;
        LOAD_A4(8192, 4);
        BARRIER; WAITLGKM; MFMA_BLK(4);
        WAITVM0;                        // last K-tile's halves must all land
        BARRIER;
        LOAD_A4(16384, 0); LOAD_B4(16384);
        BARRIER; WAITLGKM; MFMA_BLK(0); BARRIER;
        LOAD_A4(16384, 4);
        BARRIER; WAITLGKM; MFMA_BLK(4); BARRIER;
        LOAD_A4(24576, 0); LOAD_B4(24576);
        BARRIER; WAITLGKM; MFMA_BLK(0); BARRIER;
        LOAD_A4(24576, 4);
        BARRIER; WAITLGKM; MFMA_BLK(4);
    }

    // C/D layout: col = lane&15, row = (lane>>4)*4 + reg  [m89/m91]
#pragma unroll
    for (int mi = 0; mi < 8; ++mi)
#pragma unroll
        for (int ni = 0; ni < 4; ++ni)
#pragma unroll
            for (int reg = 0; reg < 4; ++reg) {
                int row = bm0 + wm * 128 + mi * 16 + q * 4 + reg;
                int col = bn0 + wn * 64 + ni * 16 + r16;
                C[(size_t)row * GLD + col] = f2bf(acc[mi][ni][reg]);
            }
}

// ---- fused row pass: softmax*relu (hat) + rh, wave-per-row, no syncs -------
__global__ __launch_bounds__(256) void row_pass(
    ushort_t* __restrict__ G, const float* __restrict__ bias_c,
    const float* __restrict__ bias_hat, const float* __restrict__ bias_r,
    const float* __restrict__ hidden, ushort_t* __restrict__ rh)
{
    const int wave = threadIdx.x >> 6, lane = threadIdx.x & 63;
    const size_t row = (size_t)blockIdx.x * 4 + wave;
    ushort_t* g = G + row * GLD;
    const int c0 = lane * 16;

    float cv[16];
    {
        short8 a = *(const short8*)(g + c0);
        short8 b = *(const short8*)(g + c0 + 8);
#pragma unroll
        for (int i = 0; i < 8; ++i) {
            cv[i]     = bf2f((ushort_t)a[i]) + bias_c[c0 + i];
            cv[8 + i] = bf2f((ushort_t)b[i]) + bias_c[c0 + 8 + i];
        }
    }
    float mx = cv[0];
#pragma unroll
    for (int i = 1; i < 16; ++i) mx = fmaxf(mx, cv[i]);
#pragma unroll
    for (int m = 1; m < 64; m <<= 1) mx = fmaxf(mx, __shfl_xor(mx, m));
    float sum = 0.f;
#pragma unroll
    for (int i = 0; i < 16; ++i) { cv[i] = __expf(cv[i] - mx); sum += cv[i]; }
#pragma unroll
    for (int m = 1; m < 64; m <<= 1) sum += __shfl_xor(sum, m);
    const float inv = 1.0f / sum;

    {
        short8 a = *(const short8*)(g + 1024 + c0);
        short8 b = *(const short8*)(g + 1024 + c0 + 8);
        short8 oa, ob;
#pragma unroll
        for (int i = 0; i < 8; ++i) {
            float ha = bf2f((ushort_t)a[i]) + bias_hat[c0 + i];
            float hb = bf2f((ushort_t)b[i]) + bias_hat[c0 + 8 + i];
            oa[i] = (short)f2bf(cv[i] * inv * fmaxf(ha, 0.f));
            ob[i] = (short)f2bf(cv[8 + i] * inv * fmaxf(hb, 0.f));
        }
        *(short8*)(g + c0) = oa;
        *(short8*)(g + c0 + 8) = ob;
    }

    {
        short8 a = *(const short8*)(g + 2048 + c0);
        short8 b = *(const short8*)(g + 2048 + c0 + 8);
        const float* hp = hidden + row * 1024 + c0;
        short8 oa, ob;
#pragma unroll
        for (int i = 0; i < 8; ++i) {
            float ra = 1.0f / (1.0f + __expf(-(bf2f((ushort_t)a[i]) + bias_r[c0 + i])));
            float rb = 1.0f / (1.0f + __expf(-(bf2f((ushort_t)b[i]) + bias_r[c0 + 8 + i])));
            oa[i] = (short)f2bf(ra * hp[i]);
            ob[i] = (short)f2bf(rb * hp[8 + i]);
        }
        ushort_t* rp = rh + row * 1024 + c0;
        *(short8*)rp = oa;
        *(short8*)(rp + 8) = ob;
    }
}

// ---- GEMM2 + fused final epilogue, 64x128 tile for TLP ---------------------
// t6 = rh @ Whh^T; out = (1-z)*tanh(xh + bias_h + t6) + z*hidden + hat
#define CSTRIDE 132
__global__ __launch_bounds__(256) void gemm2_final(
    const ushort_t* __restrict__ A, const ushort_t* __restrict__ B,
    const ushort_t* __restrict__ G, const float* __restrict__ bias_z,
    const float* __restrict__ bias_h, const float* __restrict__ hidden,
    float* __restrict__ out)
{
    const int bn0 = blockIdx.x * 128;
    const int bm0 = blockIdx.y * 64;

    __shared__ ushort_t smem[64 * CSTRIDE];   // 16.5 KiB; K-loop uses first 12 KiB
    ushort_t* As = smem;            // 64 x 32
    ushort_t* Bs = smem + 2048;     // 128 x 32

    const int t = threadIdx.x;
    const int wave = t >> 6, lane = t & 63;
    const int wr = wave >> 1, wcq = wave & 1;    // 2x2 wave grid: 32m x 64n each
    const int q = lane >> 4, r16 = lane & 15;
    const int lrow = lane >> 2;
    const int lcol = (lane & 3) * 8;

    float4v acc[2][4];
#pragma unroll
    for (int i = 0; i < 2; ++i)
#pragma unroll
        for (int j = 0; j < 4; ++j)
            acc[i][j] = {0.f, 0.f, 0.f, 0.f};

    for (int k0 = 0; k0 < 1024; k0 += 32) {
        // 12 chunks of 16 rows (A: 0..3, B: 4..11), 3 per wave
#pragma unroll
        for (int j = 0; j < 3; ++j) {
            int l = wave * 3 + j;
            if (l < 4) {
                const ushort_t* gp = A + (size_t)(bm0 + l * 16 + lrow) * 1024 + k0 + lcol;
                __builtin_amdgcn_global_load_lds(
                    (const __attribute__((address_space(1))) void*)gp,
                    (__attribute__((address_space(3))) void*)(As + l * 512),
                    16, 0, 0);
            } else {
                const ushort_t* gp = B + (size_t)(bn0 + (l - 4) * 16 + lrow) * 1024 + k0 + lcol;
                __builtin_amdgcn_global_load_lds(
                    (const __attribute__((address_space(1))) void*)gp,
                    (__attribute__((address_space(3))) void*)(Bs + (l - 4) * 512),
                    16, 0, 0);
            }
        }
        __syncthreads();

        short8 af[2], bf[4];
#pragma unroll
        for (int mi = 0; mi < 2; ++mi)
            af[mi] = *(const short8*)&As[(wr * 32 + mi * 16 + r16) * 32 + q * 8];
#pragma unroll
        for (int ni = 0; ni < 4; ++ni)
            bf[ni] = *(const short8*)&Bs[(wcq * 64 + ni * 16 + r16) * 32 + q * 8];
#pragma unroll
        for (int mi = 0; mi < 2; ++mi)
#pragma unroll
            for (int ni = 0; ni < 4; ++ni)
                acc[mi][ni] = __builtin_amdgcn_mfma_f32_16x16x32_bf16(
                    af[mi], bf[ni], acc[mi][ni], 0, 0, 0);
        __syncthreads();
    }

    // stage t6 tile to LDS (bf16), then coalesced epilogue
#pragma unroll
    for (int mi = 0; mi < 2; ++mi)
#pragma unroll
        for (int ni = 0; ni < 4; ++ni)
#pragma unroll
            for (int reg = 0; reg < 4; ++reg) {
                int rl = wr * 32 + mi * 16 + q * 4 + reg;
                int cl = wcq * 64 + ni * 16 + r16;
                smem[rl * CSTRIDE + cl] = f2bf(acc[mi][ni][reg]);
            }
    __syncthreads();

    const int colL = t & 127;
    const int gc = bn0 + colL;
    const float bz = bias_z[gc];
    const float bh = bias_h[gc];
    const int rbase = t >> 7;                  // 0 or 1
#pragma unroll 4
    for (int pass = 0; pass < 32; ++pass) {
        const int rowL = pass * 2 + rbase;
        const size_t gr = (size_t)(bm0 + rowL);
        const ushort_t* grow = G + gr * GLD;
        float z = 1.0f / (1.0f + __expf(-(bf2f(grow[3072 + gc]) + bz)));
        float targ = bf2f(grow[4096 + gc]) + bh + bf2f(smem[rowL * CSTRIDE + colL]);
        float th = 1.0f - 2.0f / (__expf(2.0f * targ) + 1.0f);
        out[gr * 1024 + gc] =
            (1.0f - z) * th + z * hidden[gr * 1024 + gc] + bf2f(grow[gc]);
    }
}

// ---- launch ----------------------------------------------------------------

extern "C" void kernel_launch(void* const* d_in, const int* in_sizes, int n_in,
                              void* d_out, int out_size, void* d_ws, size_t ws_size,
                              hipStream_t stream)
{
    const float* x        = (const float*)d_in[0];
    const float* hidden   = (const float*)d_in[1];
    const float* wxr      = (const float*)d_in[2];
    const float* whr      = (const float*)d_in[3];
    const float* bias_r   = (const float*)d_in[4];
    const float* wxz      = (const float*)d_in[5];
    const float* whz      = (const float*)d_in[6];
    const float* bias_z   = (const float*)d_in[7];
    const float* wxh      = (const float*)d_in[8];
    const float* whh      = (const float*)d_in[9];
    const float* bias_h   = (const float*)d_in[10];
    const float* wc       = (const float*)d_in[11];
    const float* bias_c   = (const float*)d_in[12];
    const float* what     = (const float*)d_in[13];
    const float* bias_hat = (const float*)d_in[14];
    float* out = (float*)d_out;

    char* ws = (char*)d_ws;
    ushort_t* G     = (ushort_t*)(ws);                    // [8192,5120] bf16, 80 MiB
    ushort_t* Abf   = (ushort_t*)(ws + 83886080);         // [8192,2048] bf16, 32 MiB
    ushort_t* Wbf   = (ushort_t*)(ws + 117440512);        // [5120,2048] bf16, 20 MiB
    ushort_t* Whhbf = (ushort_t*)(ws + 138412032);        // [1024,1024] bf16,  2 MiB
    ushort_t* rhbf  = (ushort_t*)(ws + 140509184);        // [8192,1024] bf16, 16 MiB

    pack_all<<<27648, 256, 0, stream>>>(x, hidden, wc, what, wxr, whr, wxz, whz,
                                        wxh, whh, Abf, Wbf, Whhbf);

    // GEMM1: G = Abf @ Wbf^T   (M=8192, N=5120, K=2048; xh region K=1024)
    gemm1<<<640, 512, 0, stream>>>(Abf, Wbf, G);

    // fused softmax/hat + rh (wave per row)
    row_pass<<<B_ROWS / 4, 256, 0, stream>>>(G, bias_c, bias_hat, bias_r, hidden, rhbf);

    // GEMM2 + final epilogue -> out
    gemm2_final<<<dim3(8, 128), 256, 0, stream>>>(rhbf, Whhbf, G, bias_z, bias_h,
                                                  hidden, out);
}

// Round 2
// 358.342 us; speedup vs baseline: 1.0621x; 1.0437x over previous
//
#include <hip/hip_runtime.h>

typedef unsigned short ushort_t;
typedef __attribute__((ext_vector_type(8))) short short8;
typedef __attribute__((ext_vector_type(4))) float float4v;
typedef __attribute__((ext_vector_type(4))) ushort_t ushort4v;

#define B_ROWS 8192
#define HDIM   1024
#define GLD    5120   // G cols: [hat(c) | hat_raw | r | z | xh]

__device__ __forceinline__ float bf2f(ushort_t u) {
    return __uint_as_float(((unsigned)u) << 16);
}
__device__ __forceinline__ ushort_t f2bf(float f) {
    unsigned u = __float_as_uint(f);
    u += 0x7FFFu + ((u >> 16) & 1u);   // round-to-nearest-even
    return (ushort_t)(u >> 16);
}

// ---- one pack kernel for A, W, Whh ----------------------------------------
__global__ __launch_bounds__(256) void pack_all(
    const float* __restrict__ x, const float* __restrict__ h,
    const float* __restrict__ wc, const float* __restrict__ what,
    const float* __restrict__ wxr, const float* __restrict__ whr,
    const float* __restrict__ wxz, const float* __restrict__ whz,
    const float* __restrict__ wxh, const float* __restrict__ whh,
    ushort_t* __restrict__ A, ushort_t* __restrict__ W,
    ushort_t* __restrict__ Whh)
{
    const int bid = blockIdx.x;
    float4v v;
    ushort_t* dst;
    size_t i4;
    if (bid < 16384) {                       // ---- A = [x | hidden]
        i4 = ((size_t)bid * 256 + threadIdx.x) * 4;
        int c = (int)(i4 & 2047);
        size_t b = i4 >> 11;
        const float* src = (c < 1024) ? (x + b * 1024 + c)
                                      : (h + b * 1024 + (c - 1024));
        v = *(const float4v*)src;
        dst = A + i4;
    } else if (bid < 26624) {                // ---- W rows: wc|what|[xr|hr]|[xz|hz]|[xh|junk]
        i4 = ((size_t)(bid - 16384) * 256 + threadIdx.x) * 4;
        int j = (int)(i4 >> 11);
        int k = (int)(i4 & 2047);
        int r = j >> 10, jr = j & 1023;
        if (r == 0) {
            v = *(const float4v*)(wc + (size_t)j * 2048 + k);
        } else if (r == 1) {
            v = *(const float4v*)(what + (size_t)jr * 2048 + k);
        } else if (r == 4) {
            v = (k < 1024) ? *(const float4v*)(wxh + (size_t)jr * 1024 + k)
                           : (float4v){0.f, 0.f, 0.f, 0.f};
        } else {
            const float* p0 = (r == 2) ? wxr : wxz;
            const float* p1 = (r == 2) ? whr : whz;
            const float* p = (k < 1024) ? (p0 + (size_t)jr * 1024 + k)
                                        : (p1 + (size_t)jr * 1024 + (k - 1024));
            v = *(const float4v*)p;
        }
        dst = W + i4;
    } else {                                 // ---- Whh
        i4 = ((size_t)(bid - 26624) * 256 + threadIdx.x) * 4;
        v = *(const float4v*)(whh + i4);
        dst = Whh + i4;
    }
    ushort4v o;
#pragma unroll
    for (int t = 0; t < 4; ++t) o[t] = f2bf(v[t]);
    *(ushort4v*)dst = o;
}

// ---- GEMM1: G = A @ W^T -----------------------------------------------------
// 256x256 tile, BK=64, 8 waves, quadrant-phase 8-phase schedule, counted vmcnt.
// LDS = 128 KiB = 8 half-buffers of [128 rows][64 k] bf16 (16 KiB each, 128B
// rows): A(slot,h) and B(slot,h), slot = K-tile parity. All ds_reads use the
// R0-proven zero-conflict pattern: byte = row*128 + ((kh*4+q)^(row&7))*16 with
// rows indexed by lane r16. Stage = global_load_lds 16B, source pre-swizzled
// (kc = (l&7)^(l>>3)), LDS dest linear.
// Phases per K-tile (quadrants): (A0,B0)->(A0,B1)->(A1,B1)->(A1,B0); af/bf
// fragments reused across adjacent phases (48 ds_reads / 128-k iteration).
// Staging ring (1 half-tile per phase, verified deadlines >=4 phases, WAR >=1
// barrier): P1:B(s1,0)@O P2:A(s1,1)@O P3:A(s0,0)@E' P4:B(s0,1)@E'
//           P5:B(s0,0)@E' P6:A(s0,1)@E' P7:A(s1,0)@O' P8:B(s1,1)@O'
// Uniform end-of-phase vmcnt(6) (3 half-tiles in flight), never drained.

#define GLOAD(gp, lp) __builtin_amdgcn_global_load_lds( \
    (const __attribute__((address_space(1))) void*)(gp), \
    (__attribute__((address_space(3))) void*)(lp), 16, 0, 0)

#define BARRIER __builtin_amdgcn_s_barrier()
#define WAITLGKM do { \
    asm volatile("s_waitcnt lgkmcnt(0)" ::: "memory"); \
    __builtin_amdgcn_sched_barrier(0); } while (0)
#define WAITVM6 do { \
    asm volatile("s_waitcnt vmcnt(6)" ::: "memory"); \
    __builtin_amdgcn_sched_barrier(0); } while (0)
#define WAITVM4 do { \
    asm volatile("s_waitcnt vmcnt(4)" ::: "memory"); \
    __builtin_amdgcn_sched_barrier(0); } while (0)
#define WAITVM0 do { \
    asm volatile("s_waitcnt vmcnt(0)" ::: "memory"); \
    __builtin_amdgcn_sched_barrier(0); } while (0)

// stage one 128x64 half-tile: 8 waves x 2 GLOADs x 1KB = 16KB
#define STAGE_A(S, H, KT) do { \
    GLOAD(A + aS0 + (H) * 262144 + (KT) * 64, dstA + (S) * 32768 + (H) * 8192); \
    GLOAD(A + aS1 + (H) * 262144 + (KT) * 64, dstA + (S) * 32768 + (H) * 8192 + 512); } while (0)
#define STAGE_B(S, H, KT) do { \
    GLOAD(B + bS0 + (H) * 262144 + (KT) * 64, dstB + (S) * 32768 + (H) * 8192); \
    GLOAD(B + bS1 + (H) * 262144 + (KT) * 64, dstB + (S) * 32768 + (H) * 8192 + 512); } while (0)

// 8 ds_read_b128: A-fragments for both kh of one A-half
#define LOAD_AF(S, H) do { \
    const ushort_t* _p = lds + (S) * 32768 + (H) * 8192 + aro; \
    _Pragma("unroll") \
    for (int mi = 0; mi < 4; ++mi) { \
        af0[mi] = *(const short8*)(_p + mi * 1024 + c0); \
        af1[mi] = *(const short8*)(_p + mi * 1024 + c1); } } while (0)

// 4 ds_read_b128: B-fragments for both kh of one B-half
#define LOAD_BF(V0, V1, S, H) do { \
    const ushort_t* _p = lds + (S) * 32768 + 16384 + (H) * 8192 + bro; \
    _Pragma("unroll") \
    for (int ni = 0; ni < 2; ++ni) { \
        V0[ni] = *(const short8*)(_p + ni * 1024 + c0); \
        V1[ni] = *(const short8*)(_p + ni * 1024 + c1); } } while (0)

// 16 MFMA: one quadrant (HA,HB), both kh
#define MFMA_Q(HA, HB, V0, V1) do { \
    __builtin_amdgcn_s_setprio(1); \
    _Pragma("unroll") \
    for (int mi = 0; mi < 4; ++mi) { \
        _Pragma("unroll") \
        for (int ni = 0; ni < 2; ++ni) { \
            acc[HA][HB][mi][ni] = __builtin_amdgcn_mfma_f32_16x16x32_bf16( \
                af0[mi], V0[ni], acc[HA][HB][mi][ni], 0, 0, 0); \
            acc[HA][HB][mi][ni] = __builtin_amdgcn_mfma_f32_16x16x32_bf16( \
                af1[mi], V1[ni], acc[HA][HB][mi][ni], 0, 0, 0); } } \
    __builtin_amdgcn_s_setprio(0); } while (0)

__global__ __launch_bounds__(512, 2) void gemm1(
    const ushort_t* __restrict__ A, const ushort_t* __restrict__ B,
    ushort_t* __restrict__ C)
{
    // heavy blocks (K=2048) first, light (K=1024) last; XCD-striped within each
    const int bid = blockIdx.x;
    int bx, by;
    if (bid < 512) { int hI = (bid & 7) * 64 + (bid >> 3); by = hI >> 4; bx = hI & 15; }
    else           { int b = bid - 512; int lI = (b & 7) * 16 + (b >> 3); by = lI >> 2; bx = 16 + (lI & 3); }
    const int bn0 = bx * 256;
    const int bm0 = by * 256;
    const int K = (bx >= 16) ? 1024 : 2048;
    const int NIT = K >> 7;                      // 2 K-tiles (128 k) per iter

    __shared__ ushort_t lds[65536];              // 128 KiB
    // element offsets: A(s,h) = s*32768 + h*8192 ; B(s,h) = s*32768 + 16384 + h*8192

    const int t = threadIdx.x;
    const int w = t >> 6, lane = t & 63;
    const int wm2 = w >> 2, wn2 = w & 3;         // 2 x 4 wave grid per quadrant
    const int q = lane >> 4, r16 = lane & 15;

    // ---- ds_read addressing (R0 zero-conflict pattern) ----
    const int c0 = ((q ^ (r16 & 7)) << 3);           // kh0 chunk
    const int c1 = (((4 + q) ^ (r16 & 7)) << 3);     // kh1 chunk
    const int aro = (wm2 * 64 + r16) * 64;
    const int bro = (wn2 * 32 + r16) * 64;

    // ---- staging addressing: lane l of wave w writes row w*16+g*8+(l>>3),
    //      global k-chunk (l&7)^(l>>3) (pre-swizzled source, linear LDS dest)
    const int srow0 = w * 16 + ((lane >> 3) & 7);
    const int kcO = ((lane & 7) ^ (lane >> 3)) << 3;
    const size_t aS0 = (size_t)(bm0 + srow0) * 2048 + kcO;
    const size_t aS1 = aS0 + 8 * 2048;
    const size_t bS0 = (size_t)(bn0 + srow0) * 2048 + kcO;
    const size_t bS1 = bS0 + 8 * 2048;
    ushort_t* dstA = lds + w * 1024;
    ushort_t* dstB = lds + 16384 + w * 1024;

    float4v acc[2][2][4][2];
#pragma unroll
    for (int i = 0; i < 2; ++i)
#pragma unroll
        for (int j = 0; j < 2; ++j)
#pragma unroll
            for (int m = 0; m < 4; ++m)
#pragma unroll
                for (int n = 0; n < 2; ++n)
                    acc[i][j][m][n] = {0.f, 0.f, 0.f, 0.f};

    short8 af0[4], af1[4];       // A-fragments, kh0/kh1
    short8 b00[2], b01[2];       // B-half "bf0", kh0/kh1
    short8 b10[2], b11[2];       // B-half "bf1", kh0/kh1

    // ---- prologue: K-tile0 all 4 halves + A(s1,0)@kt1 + B(s1,1)@kt1 ----
    STAGE_A(0, 0, 0);
    STAGE_B(0, 0, 0);
    STAGE_A(0, 1, 0);
    STAGE_B(0, 1, 0);
    STAGE_A(1, 0, 1);
    STAGE_B(1, 1, 1);
    WAITVM4;                                     // K-tile0's 4 halves landed
    BARRIER;

    // ---- main loop: iterations 0..NIT-2, last peeled ----
#pragma unroll 1
    for (int it = 0; it < NIT - 1; ++it) {
        const int kO  = 2 * it + 1;
        const int kE2 = 2 * it + 2;
        const int kO2 = 2 * it + 3;
        // P1: quad (A0,B0) of E | stage B(s1,0)@O
        LOAD_AF(0, 0); LOAD_BF(b00, b01, 0, 0); STAGE_B(1, 0, kO);
        BARRIER; WAITLGKM; MFMA_Q(0, 0, b00, b01); WAITVM6; BARRIER;
        // P2: quad (A0,B1) | stage A(s1,1)@O
        LOAD_BF(b10, b11, 0, 1); STAGE_A(1, 1, kO);
        BARRIER; WAITLGKM; MFMA_Q(0, 1, b10, b11); WAITVM6; BARRIER;
        // P3: quad (A1,B1) | stage A(s0,0)@E'
        LOAD_AF(0, 1); STAGE_A(0, 0, kE2);
        BARRIER; WAITLGKM; MFMA_Q(1, 1, b10, b11); WAITVM6; BARRIER;
        // P4: quad (A1,B0) (all regs live) | stage B(s0,1)@E'
        STAGE_B(0, 1, kE2);
        BARRIER; MFMA_Q(1, 0, b00, b01); WAITVM6; BARRIER;
        // P5: quad (A0,B0) of O | stage B(s0,0)@E'
        LOAD_AF(1, 0); LOAD_BF(b00, b01, 1, 0); STAGE_B(0, 0, kE2);
        BARRIER; WAITLGKM; MFMA_Q(0, 0, b00, b01); WAITVM6; BARRIER;
        // P6: quad (A0,B1) | stage A(s0,1)@E'
        LOAD_BF(b10, b11, 1, 1); STAGE_A(0, 1, kE2);
        BARRIER; WAITLGKM; MFMA_Q(0, 1, b10, b11); WAITVM6; BARRIER;
        // P7: quad (A1,B1) | stage A(s1,0)@O'
        LOAD_AF(1, 1); STAGE_A(1, 0, kO2);
        BARRIER; WAITLGKM; MFMA_Q(1, 1, b10, b11); WAITVM6; BARRIER;
        // P8: quad (A1,B0) | stage B(s1,1)@O'
        STAGE_B(1, 1, kO2);
        BARRIER; MFMA_Q(1, 0, b00, b01); WAITVM6; BARRIER;
    }

    // ---- peeled last iteration (E = 2NIT-2, O = 2NIT-1) ----
    {
        const int kO = 2 * (NIT - 1) + 1;
        LOAD_AF(0, 0); LOAD_BF(b00, b01, 0, 0); STAGE_B(1, 0, kO);
        BARRIER; WAITLGKM; MFMA_Q(0, 0, b00, b01); WAITVM6; BARRIER;
        LOAD_BF(b10, b11, 0, 1); STAGE_A(1, 1, kO);
        BARRIER; WAITLGKM; MFMA_Q(0, 1, b10, b11); WAITVM6; BARRIER;
        LOAD_AF(0, 1);
        WAITLGKM; MFMA_Q(1, 1, b10, b11);
        MFMA_Q(1, 0, b00, b01);
        WAITVM0;                                 // all of O's halves in LDS
        BARRIER;
        LOAD_AF(1, 0); LOAD_BF(b00, b01, 1, 0);
        WAITLGKM; MFMA_Q(0, 0, b00, b01);
        LOAD_BF(b10, b11, 1, 1);
        WAITLGKM; MFMA_Q(0, 1, b10, b11);
        LOAD_AF(1, 1);
        WAITLGKM; MFMA_Q(1, 1, b10, b11);
        MFMA_Q(1, 0, b00, b01);
    }

    // C/D layout: col = lane&15, row = (lane>>4)*4 + reg  [m89/m91]
#pragma unroll
    for (int ha = 0; ha < 2; ++ha)
#pragma unroll
        for (int hb = 0; hb < 2; ++hb)
#pragma unroll
            for (int mi = 0; mi < 4; ++mi)
#pragma unroll
                for (int ni = 0; ni < 2; ++ni)
#pragma unroll
                    for (int reg = 0; reg < 4; ++reg) {
                        int row = bm0 + ha * 128 + wm2 * 64 + mi * 16 + q * 4 + reg;
                        int col = bn0 + hb * 128 + wn2 * 32 + ni * 16 + r16;
                        C[(size_t)row * GLD + col] = f2bf(acc[ha][hb][mi][ni][reg]);
                    }
}

// ---- fused row pass: softmax*relu (hat) + rh, wave-per-row, no syncs -------
__global__ __launch_bounds__(256) void row_pass(
    ushort_t* __restrict__ G, const float* __restrict__ bias_c,
    const float* __restrict__ bias_hat, const float* __restrict__ bias_r,
    const float* __restrict__ hidden, ushort_t* __restrict__ rh)
{
    const int wave = threadIdx.x >> 6, lane = threadIdx.x & 63;
    const size_t row = (size_t)blockIdx.x * 4 + wave;
    ushort_t* g = G + row * GLD;
    const int c0 = lane * 16;

    float cv[16];
    {
        short8 a = *(const short8*)(g + c0);
        short8 b = *(const short8*)(g + c0 + 8);
#pragma unroll
        for (int i = 0; i < 8; ++i) {
            cv[i]     = bf2f((ushort_t)a[i]) + bias_c[c0 + i];
            cv[8 + i] = bf2f((ushort_t)b[i]) + bias_c[c0 + 8 + i];
        }
    }
    float mx = cv[0];
#pragma unroll
    for (int i = 1; i < 16; ++i) mx = fmaxf(mx, cv[i]);
#pragma unroll
    for (int m = 1; m < 64; m <<= 1) mx = fmaxf(mx, __shfl_xor(mx, m));
    float sum = 0.f;
#pragma unroll
    for (int i = 0; i < 16; ++i) { cv[i] = __expf(cv[i] - mx); sum += cv[i]; }
#pragma unroll
    for (int m = 1; m < 64; m <<= 1) sum += __shfl_xor(sum, m);
    const float inv = 1.0f / sum;

    {
        short8 a = *(const short8*)(g + 1024 + c0);
        short8 b = *(const short8*)(g + 1024 + c0 + 8);
        short8 oa, ob;
#pragma unroll
        for (int i = 0; i < 8; ++i) {
            float ha = bf2f((ushort_t)a[i]) + bias_hat[c0 + i];
            float hb = bf2f((ushort_t)b[i]) + bias_hat[c0 + 8 + i];
            oa[i] = (short)f2bf(cv[i] * inv * fmaxf(ha, 0.f));
            ob[i] = (short)f2bf(cv[8 + i] * inv * fmaxf(hb, 0.f));
        }
        *(short8*)(g + c0) = oa;
        *(short8*)(g + c0 + 8) = ob;
    }

    {
        short8 a = *(const short8*)(g + 2048 + c0);
        short8 b = *(const short8*)(g + 2048 + c0 + 8);
        const float* hp = hidden + row * 1024 + c0;
        short8 oa, ob;
#pragma unroll
        for (int i = 0; i < 8; ++i) {
            float ra = 1.0f / (1.0f + __expf(-(bf2f((ushort_t)a[i]) + bias_r[c0 + i])));
            float rb = 1.0f / (1.0f + __expf(-(bf2f((ushort_t)b[i]) + bias_r[c0 + 8 + i])));
            oa[i] = (short)f2bf(ra * hp[i]);
            ob[i] = (short)f2bf(rb * hp[8 + i]);
        }
        ushort_t* rp = rh + row * 1024 + c0;
        *(short8*)rp = oa;
        *(short8*)(rp + 8) = ob;
    }
}

// ---- GEMM2 + fused final epilogue, 64x128 tile for TLP ---------------------
// t6 = rh @ Whh^T; out = (1-z)*tanh(xh + bias_h + t6) + z*hidden + hat
#define CSTRIDE 132
__global__ __launch_bounds__(256) void gemm2_final(
    const ushort_t* __restrict__ A, const ushort_t* __restrict__ B,
    const ushort_t* __restrict__ G, const float* __restrict__ bias_z,
    const float* __restrict__ bias_h, const float* __restrict__ hidden,
    float* __restrict__ out)
{
    const int bn0 = blockIdx.x * 128;
    const int bm0 = blockIdx.y * 64;

    __shared__ ushort_t smem[64 * CSTRIDE];   // 16.5 KiB; K-loop uses first 12 KiB
    ushort_t* As = smem;            // 64 x 32
    ushort_t* Bs = smem + 2048;     // 128 x 32

    const int t = threadIdx.x;
    const int wave = t >> 6, lane = t & 63;
    const int wr = wave >> 1, wcq = wave & 1;    // 2x2 wave grid: 32m x 64n each
    const int q = lane >> 4, r16 = lane & 15;
    const int lrow = lane >> 2;
    const int lcol = (lane & 3) * 8;

    float4v acc[2][4];
#pragma unroll
    for (int i = 0; i < 2; ++i)
#pragma unroll
        for (int j = 0; j < 4; ++j)
            acc[i][j] = {0.f, 0.f, 0.f, 0.f};

    for (int k0 = 0; k0 < 1024; k0 += 32) {
        // 12 chunks of 16 rows (A: 0..3, B: 4..11), 3 per wave
#pragma unroll
        for (int j = 0; j < 3; ++j) {
            int l = wave * 3 + j;
            if (l < 4) {
                const ushort_t* gp = A + (size_t)(bm0 + l * 16 + lrow) * 1024 + k0 + lcol;
                __builtin_amdgcn_global_load_lds(
                    (const __attribute__((address_space(1))) void*)gp,
                    (__attribute__((address_space(3))) void*)(As + l * 512),
                    16, 0, 0);
            } else {
                const ushort_t* gp = B + (size_t)(bn0 + (l - 4) * 16 + lrow) * 1024 + k0 + lcol;
                __builtin_amdgcn_global_load_lds(
                    (const __attribute__((address_space(1))) void*)gp,
                    (__attribute__((address_space(3))) void*)(Bs + (l - 4) * 512),
                    16, 0, 0);
            }
        }
        __syncthreads();

        short8 af[2], bf[4];
#pragma unroll
        for (int mi = 0; mi < 2; ++mi)
            af[mi] = *(const short8*)&As[(wr * 32 + mi * 16 + r16) * 32 + q * 8];
#pragma unroll
        for (int ni = 0; ni < 4; ++ni)
            bf[ni] = *(const short8*)&Bs[(wcq * 64 + ni * 16 + r16) * 32 + q * 8];
#pragma unroll
        for (int mi = 0; mi < 2; ++mi)
#pragma unroll
            for (int ni = 0; ni < 4; ++ni)
                acc[mi][ni] = __builtin_amdgcn_mfma_f32_16x16x32_bf16(
                    af[mi], bf[ni], acc[mi][ni], 0, 0, 0);
        __syncthreads();
    }

    // stage t6 tile to LDS (bf16), then coalesced epilogue
#pragma unroll
    for (int mi = 0; mi < 2; ++mi)
#pragma unroll
        for (int ni = 0; ni < 4; ++ni)
#pragma unroll
            for (int reg = 0; reg < 4; ++reg) {
                int rl = wr * 32 + mi * 16 + q * 4 + reg;
                int cl = wcq * 64 + ni * 16 + r16;
                smem[rl * CSTRIDE + cl] = f2bf(acc[mi][ni][reg]);
            }
    __syncthreads();

    const int colL = t & 127;
    const int gc = bn0 + colL;
    const float bz = bias_z[gc];
    const float bh = bias_h[gc];
    const int rbase = t >> 7;                  // 0 or 1
#pragma unroll 4
    for (int pass = 0; pass < 32; ++pass) {
        const int rowL = pass * 2 + rbase;
        const size_t gr = (size_t)(bm0 + rowL);
        const ushort_t* grow = G + gr * GLD;
        float z = 1.0f / (1.0f + __expf(-(bf2f(grow[3072 + gc]) + bz)));
        float targ = bf2f(grow[4096 + gc]) + bh + bf2f(smem[rowL * CSTRIDE + colL]);
        float th = 1.0f - 2.0f / (__expf(2.0f * targ) + 1.0f);
        out[gr * 1024 + gc] =
            (1.0f - z) * th + z * hidden[gr * 1024 + gc] + bf2f(grow[gc]);
    }
}

// ---- launch ----------------------------------------------------------------

extern "C" void kernel_launch(void* const* d_in, const int* in_sizes, int n_in,
                              void* d_out, int out_size, void* d_ws, size_t ws_size,
                              hipStream_t stream)
{
    const float* x        = (const float*)d_in[0];
    const float* hidden   = (const float*)d_in[1];
    const float* wxr      = (const float*)d_in[2];
    const float* whr      = (const float*)d_in[3];
    const float* bias_r   = (const float*)d_in[4];
    const float* wxz      = (const float*)d_in[5];
    const float* whz      = (const float*)d_in[6];
    const float* bias_z   = (const float*)d_in[7];
    const float* wxh      = (const float*)d_in[8];
    const float* whh      = (const float*)d_in[9];
    const float* bias_h   = (const float*)d_in[10];
    const float* wc       = (const float*)d_in[11];
    const float* bias_c   = (const float*)d_in[12];
    const float* what     = (const float*)d_in[13];
    const float* bias_hat = (const float*)d_in[14];
    float* out = (float*)d_out;

    char* ws = (char*)d_ws;
    ushort_t* G     = (ushort_t*)(ws);                    // [8192,5120] bf16, 80 MiB
    ushort_t* Abf   = (ushort_t*)(ws + 83886080);         // [8192,2048] bf16, 32 MiB
    ushort_t* Wbf   = (ushort_t*)(ws + 117440512);        // [5120,2048] bf16, 20 MiB
    ushort_t* Whhbf = (ushort_t*)(ws + 138412032);        // [1024,1024] bf16,  2 MiB
    ushort_t* rhbf  = (ushort_t*)(ws + 140509184);        // [8192,1024] bf16, 16 MiB

    pack_all<<<27648, 256, 0, stream>>>(x, hidden, wc, what, wxr, whr, wxz, whz,
                                        wxh, whh, Abf, Wbf, Whhbf);

    // GEMM1: G = Abf @ Wbf^T   (M=8192, N=5120, K=2048; xh region K=1024)
    gemm1<<<640, 512, 0, stream>>>(Abf, Wbf, G);

    // fused softmax/hat + rh (wave per row)
    row_pass<<<B_ROWS / 4, 256, 0, stream>>>(G, bias_c, bias_hat, bias_r, hidden, rhbf);

    // GEMM2 + final epilogue -> out
    gemm2_final<<<dim3(8, 128), 256, 0, stream>>>(rhbf, Whhbf, G, bias_z, bias_h,
                                                  hidden, out);
}